// Round 7
// baseline (122188.281 us; speedup 1.0000x reference)
//
#include <hip/hip_runtime.h>
#include <math.h>

// Problem constants (fixed by the reference)
#define BQ 32
#define DQ 512
#define TQ 2048
#define VQ 1024
#define QQ 6
#define NQ (BQ * TQ)                 // 65536 rows
#define NDQ ((size_t)NQ * DQ)        // 33,554,432 elements

// ---------------------------------------------------------------------------
// B-tile LDS swizzle (layout only; values untouched)
__device__ __forceinline__ int bswz(int kk, int vv) {
    return vv ^ ((((kk & 7) ^ ((vv >> 5) & 7))) << 2);
}

// ---------------------------------------------------------------------------
// numpy-pairwise fp32 ||c||^2: per 512-row = (P0+P1)+(P2+P3), each P = 128-block
// with 8 accumulators + ((r0+r1)+(r2+r3))+((r4+r5)+(r6+r7)) tree. 32 lanes/code.
__global__ void cnorm32_kernel(const float* __restrict__ cb, float* __restrict__ cn) {
    #pragma clang fp contract(off)
    int gw   = (blockIdx.x * blockDim.x + threadIdx.x) >> 5;  // 32-lane group
    int l    = threadIdx.x & 31;
    if (gw >= QQ * VQ) return;
    const float* row = cb + (size_t)gw * DQ;
    const int c = l >> 3, j = l & 7;
    float acc = 0.f;
    #pragma unroll
    for (int m = 0; m < 16; m++) {
        float v = row[c * 128 + m * 8 + j];
        float a = v * v;          // separate fp32 round (numpy temp array)
        acc = acc + a;            // sequential ascending m
    }
    float s = acc + __shfl_xor(acc, 1, 64);   // (r0+r1) etc.
    s = s + __shfl_xor(s, 2, 64);             // +(r2+r3) pair
    s = s + __shfl_xor(s, 4, 64);             // full 8-tree -> Pc
    float t = s + __shfl_xor(s, 8, 64);       // (P0+P1), (P2+P3)
    t = t + __shfl_xor(t, 16, 64);            // (P0+P1)+(P2+P3)
    if (l == 0) cn[gw] = t;
}

// ---------------------------------------------------------------------------
// One residual-VQ stage, fp32 numpy-replicated index pipeline.
// 128 rows x 256 codes per block, BK=16, 16x8 micro-tile (0.75 B/FMA from LDS),
// double-buffered issue-early/write-late pipeline.
__global__ __launch_bounds__(256, 2) void vq32_pass(
    const float* __restrict__ x, const float* __restrict__ cb_all,
    const float* __restrict__ cn_all,
    float* __restrict__ res,       // d_out base; residual chain, final: quantized
    float* __restrict__ idx_out,   // d_out + ND + 3, (B,T,Q) as float
    int* __restrict__ hist, double* __restrict__ loss_acc, int q)
{
    #pragma clang fp contract(off)
    __shared__ float As[2][16][128];    // 16 KiB
    __shared__ float Bs[2][16][256];    // 32 KiB; phase-2 reuse as c2[128][64]
    __shared__ int   idx_l[128];
    __shared__ float PL[128][4];
    __shared__ float rn_l[128];
    __shared__ double redbuf[4];

    const int tid = threadIdx.x;
    const int n0  = blockIdx.x * 128;
    const int b   = n0 / TQ;
    const int t0  = n0 % TQ;
    const float* cb  = cb_all + (size_t)q * VQ * DQ;
    const float* cn  = cn_all + q * VQ;
    const float* src = (q == 0) ? x : res;

    const int rr  = tid & 127;          // A staging: row
    const int kh  = tid >> 7;           // A staging: k-half (8 k's)
    const int kks = tid & 15;           // B staging: k
    const int vbs = tid >> 4;           // B staging: code subgroup (16 codes)
    const int ty  = tid >> 5;           // compute: 8 row groups x 16 rows
    const int tx  = tid & 31;           // compute: 32 code groups x 8 codes

    float aR[8], bR[16];

    auto loadA = [&](int kt) {
        const float* sp = src + ((size_t)b * DQ + kt * 16 + kh * 8) * TQ + t0 + rr;
        #pragma unroll
        for (int u = 0; u < 8; u++) aR[u] = sp[(size_t)u * TQ];
    };
    auto loadB = [&](int vt, int kt) {
        const float* bp = cb + (size_t)(vt * 256 + vbs * 16) * DQ + kt * 16 + kks;
        #pragma unroll
        for (int w = 0; w < 16; w++) bR[w] = bp[(size_t)w * DQ];
    };
    auto writeA = [&](int bf) {
        #pragma unroll
        for (int u = 0; u < 8; u++) As[bf][kh * 8 + u][rr] = aR[u];
    };
    auto writeB = [&](int bf) {
        #pragma unroll
        for (int w = 0; w < 16; w++) Bs[bf][kks][bswz(kks, vbs * 16 + w)] = bR[w];
    };

    // rn chunk-partials (two chunks per thread, statically indexed)
    float rx0[8], rx1[8];
    #pragma unroll
    for (int j = 0; j < 8; j++) { rx0[j] = 0.f; rx1[j] = 0.f; }

    float best[16]; int bidx[16];
    #pragma unroll
    for (int i = 0; i < 16; i++) { best[i] = INFINITY; bidx[i] = 0; }

    // pipeline prologue: stage (vt=0, kt=0) into buffer 0
    loadA(0); loadB(0, 0);
    writeA(0); writeB(0);

    for (int vt = 0; vt < 4; vt++) {
        float acc[16][8];
        #pragma unroll
        for (int i = 0; i < 16; i++)
            #pragma unroll
            for (int j = 0; j < 8; j++) acc[i][j] = 0.f;

        int cur = 0;
        for (int kt = 0; kt < 32; kt++) {
            if (kt < 31) { loadA(kt + 1); loadB(vt, kt + 1); }   // issue early
            __syncthreads();                                     // buf[cur] ready
            // strict ascending-k fp32 FMA chain per (row,code) — BLAS order
            #pragma unroll
            for (int kk = 0; kk < 16; kk++) {
                const float4 a0 = *(const float4*)&As[cur][kk][ty * 16];
                const float4 a1 = *(const float4*)&As[cur][kk][ty * 16 + 4];
                const float4 a2 = *(const float4*)&As[cur][kk][ty * 16 + 8];
                const float4 a3 = *(const float4*)&As[cur][kk][ty * 16 + 12];
                const float4 b0 = *(const float4*)&Bs[cur][kk][bswz(kk, tx * 8)];
                const float4 b1 = *(const float4*)&Bs[cur][kk][bswz(kk, tx * 8 + 4)];
                const float av[16] = {a0.x,a0.y,a0.z,a0.w, a1.x,a1.y,a1.z,a1.w,
                                      a2.x,a2.y,a2.z,a2.w, a3.x,a3.y,a3.z,a3.w};
                const float bv[8]  = {b0.x,b0.y,b0.z,b0.w, b1.x,b1.y,b1.z,b1.w};
                #pragma unroll
                for (int i = 0; i < 16; i++)
                    #pragma unroll
                    for (int j = 0; j < 8; j++)
                        acc[i][j] = fmaf(av[i], bv[j], acc[i][j]);
            }
            // merged rn pass (vt==0): numpy 128-chunk, 8 accs, ascending m
            if (vt == 0 && (kt >> 4) == kh) {
                if (((kt >> 3) & 1) == 0) {
                    #pragma unroll
                    for (int mm = 0; mm < 2; mm++)
                        #pragma unroll
                        for (int j2 = 0; j2 < 8; j2++) {
                            float v = As[cur][mm * 8 + j2][rr];
                            float a2v = v * v;
                            rx0[j2] = rx0[j2] + a2v;
                        }
                } else {
                    #pragma unroll
                    for (int mm = 0; mm < 2; mm++)
                        #pragma unroll
                        for (int j2 = 0; j2 < 8; j2++) {
                            float v = As[cur][mm * 8 + j2][rr];
                            float a2v = v * v;
                            rx1[j2] = rx1[j2] + a2v;
                        }
                }
            }
            if (kt < 31) { writeA(cur ^ 1); writeB(cur ^ 1); }   // write late
            cur ^= 1;
        }

        if (vt == 0) {
            // finish rn: 8-acc tree per chunk, then (P0+P1)+(P2+P3)
            {
                float s01 = rx0[0] + rx0[1], s23 = rx0[2] + rx0[3];
                float s45 = rx0[4] + rx0[5], s67 = rx0[6] + rx0[7];
                PL[rr][kh * 2 + 0] = (s01 + s23) + (s45 + s67);
            }
            {
                float s01 = rx1[0] + rx1[1], s23 = rx1[2] + rx1[3];
                float s45 = rx1[4] + rx1[5], s67 = rx1[6] + rx1[7];
                PL[rr][kh * 2 + 1] = (s01 + s23) + (s45 + s67);
            }
            __syncthreads();
            if (tid < 128) {
                float a01 = PL[tid][0] + PL[tid][1];
                float a23 = PL[tid][2] + PL[tid][3];
                rn_l[tid] = a01 + a23;
            }
            __syncthreads();
        }

        // prefetch next vt's first tile (hidden under fold)
        if (vt < 3) { loadA(0); loadB(vt + 1, 0); }

        // fold: d = fl(fl(rn - 2M) + cn), first-min over ascending v
        #pragma unroll
        for (int j = 0; j < 8; j++) {
            const int v = vt * 256 + tx * 8 + j;
            const float cnv = cn[v];
            #pragma unroll
            for (int i = 0; i < 16; i++) {
                float m2 = 2.0f * acc[i][j];
                float t1 = rn_l[ty * 16 + i] - m2;
                float d  = t1 + cnv;
                if (d < best[i]) { best[i] = d; bidx[i] = v; }
            }
        }

        if (vt < 3) { writeA(0); writeB(0); }   // safe: buf0 idle since kt=30
    }

    // (min, argmin) butterfly with first-index tie rule (32 lanes per ty)
    #pragma unroll
    for (int i = 0; i < 16; i++) {
        float v = best[i]; int ix = bidx[i];
        #pragma unroll
        for (int m = 16; m >= 1; m >>= 1) {
            float ov = __shfl_xor(v, m, 64);
            int   oi = __shfl_xor(ix, m, 64);
            if (ov < v || (ov == v && oi < ix)) { v = ov; ix = oi; }
        }
        if (tx == 0) idx_l[ty * 16 + i] = ix;
    }
    __syncthreads();

    if (tid < 128) {
        int ix = idx_l[tid];
        idx_out[(size_t)(n0 + tid) * QQ + q] = (float)ix;
        atomicAdd(&hist[q * VQ + ix], 1);
    }

    // ---------- Phase 2: residual update + loss (+ final output) ----------
    float* c2 = &Bs[0][0][0];   // reuse as [128 rows][64 k] with XOR swizzle
    double lsum = 0.0;
    for (int kc = 0; kc < 8; kc++) {
        __syncthreads();
        {   // stage the selected code rows (coalesced 256B per row)
            int kk3 = tid & 63, r4 = tid >> 6;
            #pragma unroll
            for (int p = 0; p < 32; p++) {
                int rw = p * 4 + r4;
                const float* crow = cb + (size_t)idx_l[rw] * DQ + kc * 64;
                c2[rw * 64 + (kk3 ^ (rw & 31))] = crow[kk3];
            }
        }
        __syncthreads();
        {
            int kb2 = tid >> 7;   // 0..1 : 32 k's each
            #pragma unroll
            for (int w = 0; w < 32; w++) {
                int kk = kb2 * 32 + w;
                int k  = kc * 64 + kk;
                size_t o = ((size_t)b * DQ + k) * TQ + t0 + rr;
                float cv = c2[rr * 64 + (kk ^ (rr & 31))];
                float r_old = src[o];          // x at q==0, else stored residual
                float e  = r_old - cv;         // loss term (exact ref chain)
                lsum += (double)e * (double)e;
                float tt = cv - r_old;
                float qs = r_old + tt;         // quant_st, fp32 reference chain
                float rn2 = r_old - qs;        // updated residual
                if (q < QQ - 1) res[o] = rn2;
                else            res[o] = x[o] - rn2;   // quantized_out = x - r_final
            }
        }
    }
    #pragma unroll
    for (int m = 32; m >= 1; m >>= 1) lsum += __shfl_xor(lsum, m, 64);
    if ((tid & 63) == 0) redbuf[tid >> 6] = lsum;
    __syncthreads();
    if (tid == 0)
        atomicAdd(loss_acc + q, redbuf[0] + redbuf[1] + redbuf[2] + redbuf[3]);
}

// ---------------------------------------------------------------------------
// Scalars: usage%, loss, perplexity averaged over Q.
__global__ void finalize_kernel(const int* __restrict__ hist,
                                const double* __restrict__ loss_acc,
                                float* __restrict__ outs) {
    int lane = threadIdx.x;  // blockDim = 64
    float usage_sum = 0.f, perp_sum = 0.f;
    for (int q = 0; q < QQ; q++) {
        int nz = 0; float ent = 0.f;
        for (int v = lane; v < VQ; v += 64) {
            int c = hist[q * VQ + v];
            if (c > 0) {
                nz++;
                float p = (float)c / (float)NQ;
                ent += p * logf(p);
            }
        }
        #pragma unroll
        for (int m = 32; m >= 1; m >>= 1) {
            nz  += __shfl_xor(nz, m, 64);
            ent += __shfl_xor(ent, m, 64);
        }
        usage_sum += (float)nz / (float)VQ * 100.f;
        perp_sum  += expf(-ent);
    }
    if (lane == 0) {
        outs[0] = usage_sum / QQ;
        double ls = 0.0;
        for (int q = 0; q < QQ; q++)
            ls += loss_acc[q] * 1.25 / (double)NDQ;
        outs[1] = (float)(ls / QQ);
        outs[2] = perp_sum / QQ;
    }
}

// ---------------------------------------------------------------------------
extern "C" void kernel_launch(void* const* d_in, const int* in_sizes, int n_in,
                              void* d_out, int out_size, void* d_ws, size_t ws_size,
                              hipStream_t stream) {
    const float* x  = (const float*)d_in[0];
    const float* cb = (const float*)d_in[1];

    float* res     = (float*)d_out;          // [0, ND): residual -> quantized_out
    float* scal    = res + NDQ;              // usage, loss, perp
    float* idx_out = scal + 3;               // (B,T,Q) indices as float

    int*    hist     = (int*)d_ws;                                     // Q*V ints
    double* loss_acc = (double*)((char*)d_ws + QQ * VQ * sizeof(int)); // Q doubles
    float*  cn32     = (float*)(loss_acc + QQ);                        // Q*V floats

    hipMemsetAsync(d_ws, 0, QQ * VQ * sizeof(int) + QQ * sizeof(double), stream);

    cnorm32_kernel<<<(QQ * VQ) / 8, 256, 0, stream>>>(cb, cn32);

    for (int q = 0; q < QQ; q++) {
        vq32_pass<<<NQ / 128, 256, 0, stream>>>(x, cb, cn32, res, idx_out,
                                                hist, loss_acc, q);
    }

    finalize_kernel<<<1, 64, 0, stream>>>(hist, loss_acc, scal);
}

// Round 8
// 10462.990 us; speedup vs baseline: 11.6781x; 11.6781x over previous
//
#include <hip/hip_runtime.h>
#include <math.h>

// Problem constants (fixed by the reference)
#define BQ 32
#define DQ 512
#define TQ 2048
#define VQ 1024
#define QQ 6
#define NQ (BQ * TQ)                 // 65536 rows
#define NDQ ((size_t)NQ * DQ)        // 33,554,432 elements

// ---------------------------------------------------------------------------
// B-tile LDS swizzle (layout only; values untouched)
__device__ __forceinline__ int bswz(int kk, int vv) {
    return vv ^ ((((kk & 7) ^ ((vv >> 5) & 7))) << 2);
}

// async global->LDS, one dword per lane (dest = lds_base + lane*4)
__device__ __forceinline__ void gll4(const float* g, float* l) {
    __builtin_amdgcn_global_load_lds(
        (const __attribute__((address_space(1))) void*)g,
        (__attribute__((address_space(3))) void*)l, 4, 0, 0);
}

// ---------------------------------------------------------------------------
// numpy-pairwise fp32 ||c||^2: per 512-row = (P0+P1)+(P2+P3), each P = 128-block
// with 8 accumulators + ((r0+r1)+(r2+r3))+((r4+r5)+(r6+r7)) tree. 32 lanes/code.
__global__ void cnorm32_kernel(const float* __restrict__ cb, float* __restrict__ cn) {
    #pragma clang fp contract(off)
    int gw   = (blockIdx.x * blockDim.x + threadIdx.x) >> 5;  // 32-lane group
    int l    = threadIdx.x & 31;
    if (gw >= QQ * VQ) return;
    const float* row = cb + (size_t)gw * DQ;
    const int c = l >> 3, j = l & 7;
    float acc = 0.f;
    #pragma unroll
    for (int m = 0; m < 16; m++) {
        float v = row[c * 128 + m * 8 + j];
        float a = v * v;          // separate fp32 round (numpy temp array)
        acc = acc + a;            // sequential ascending m
    }
    float s = acc + __shfl_xor(acc, 1, 64);   // (r0+r1) etc.
    s = s + __shfl_xor(s, 2, 64);             // +(r2+r3) pair
    s = s + __shfl_xor(s, 4, 64);             // full 8-tree -> Pc
    float t = s + __shfl_xor(s, 8, 64);       // (P0+P1), (P2+P3)
    t = t + __shfl_xor(t, 16, 64);            // (P0+P1)+(P2+P3)
    if (l == 0) cn[gw] = t;
}

// ---------------------------------------------------------------------------
// One residual-VQ stage, fp32 numpy-replicated index pipeline.
// 64 rows x 256 codes per block, BK=16, 8x8 micro-tile (1.0 B/lane/FMA),
// double-buffered; A staged by global_load_lds, B reg-staged (swizzled).
__global__ __launch_bounds__(256) void vq32_pass(
    const float* __restrict__ x, const float* __restrict__ cb_all,
    const float* __restrict__ cn_all,
    float* __restrict__ res,       // d_out base; residual chain, final: quantized
    float* __restrict__ idx_out,   // d_out + ND + 3, (B,T,Q) as float
    int* __restrict__ hist, double* __restrict__ loss_acc, int q)
{
    #pragma clang fp contract(off)
    __shared__ float As[2][16][64];     // 8 KiB
    __shared__ float Bs[2][16][256];    // 32 KiB; phase-2 reuse as c2[64][128]
    __shared__ int   idx_l[64];
    __shared__ float PL[64][4];
    __shared__ float rn_l[64];
    __shared__ double redbuf[4];

    const int tid = threadIdx.x;
    const int n0  = blockIdx.x * 64;
    const int b   = n0 / TQ;
    const int t0  = n0 % TQ;
    const float* cb  = cb_all + (size_t)q * VQ * DQ;
    const float* cn  = cn_all + q * VQ;
    const float* src = (q == 0) ? x : res;

    const int lane = tid & 63;          // row (staging + rn + phase 2)
    const int wv   = tid >> 6;          // wave id = rn chunk = A-staging group
    const int kks  = tid & 15;          // B staging: k
    const int vbs  = tid >> 4;          // B staging: code subgroup (16 codes)
    const int ty   = tid >> 5;          // compute: 8 row groups x 8 rows
    const int tx   = tid & 31;          // compute: 32 code groups x 8 codes

    float bR[16];

    auto loadB = [&](int vt, int kt) {
        const float* bp = cb + (size_t)(vt * 256 + vbs * 16) * DQ + kt * 16 + kks;
        #pragma unroll
        for (int w = 0; w < 16; w++) bR[w] = bp[(size_t)w * DQ];
    };
    auto writeB = [&](int bf) {
        #pragma unroll
        for (int w = 0; w < 16; w++) Bs[bf][kks][bswz(kks, vbs * 16 + w)] = bR[w];
    };
    auto stageA = [&](int kt, int bf) {     // async DMA, wave wv owns 4 kk-rows
        #pragma unroll
        for (int u = 0; u < 4; u++) {
            int kk = wv * 4 + u;
            const float* gp = src + ((size_t)b * DQ + kt * 16 + kk) * TQ + t0 + lane;
            gll4(gp, &As[bf][kk][0]);
        }
    };

    float racc[8];
    #pragma unroll
    for (int j = 0; j < 8; j++) racc[j] = 0.f;

    float best[8]; int bidx[8];
    #pragma unroll
    for (int i = 0; i < 8; i++) { best[i] = INFINITY; bidx[i] = 0; }

    // prologue: stage (vt=0, kt=0) into buffer 0
    loadB(0, 0); writeB(0);
    stageA(0, 0);

    for (int vt = 0; vt < 4; vt++) {
        float acc[8][8];
        #pragma unroll
        for (int i = 0; i < 8; i++)
            #pragma unroll
            for (int j = 0; j < 8; j++) acc[i][j] = 0.f;

        int cur = 0;
        for (int kt = 0; kt < 32; kt++) {
            if (kt < 31) loadB(vt, kt + 1);          // issue B early (regs)
            __syncthreads();                          // buf[cur] ready (gll drained)
            if (kt < 31) stageA(kt + 1, cur ^ 1);     // async A into other buffer
            // strict ascending-k fp32 FMA chain per (row,code) — BLAS order
            #pragma unroll
            for (int kk = 0; kk < 16; kk++) {
                const float4 a0 = *(const float4*)&As[cur][kk][ty * 8];
                const float4 a1 = *(const float4*)&As[cur][kk][ty * 8 + 4];
                const float4 b0 = *(const float4*)&Bs[cur][kk][bswz(kk, tx * 8)];
                const float4 b1 = *(const float4*)&Bs[cur][kk][bswz(kk, tx * 8 + 4)];
                const float av[8] = {a0.x,a0.y,a0.z,a0.w, a1.x,a1.y,a1.z,a1.w};
                const float bv[8] = {b0.x,b0.y,b0.z,b0.w, b1.x,b1.y,b1.z,b1.w};
                #pragma unroll
                for (int i = 0; i < 8; i++)
                    #pragma unroll
                    for (int j = 0; j < 8; j++)
                        acc[i][j] = fmaf(av[i], bv[j], acc[i][j]);
            }
            // merged rn pass (vt==0): numpy 128-chunk (= wave id), 8 accs,
            // ascending m; wave-uniform branch
            if (vt == 0 && (kt >> 3) == wv) {
                #pragma unroll
                for (int mm = 0; mm < 2; mm++)
                    #pragma unroll
                    for (int j2 = 0; j2 < 8; j2++) {
                        float v  = As[cur][mm * 8 + j2][lane];
                        float a2 = v * v;
                        racc[j2] = racc[j2] + a2;
                    }
            }
            if (kt < 31) writeB(cur ^ 1);             // write B late
            cur ^= 1;
        }

        if (vt == 0) {
            // finish rn: 8-acc tree per 128-chunk, then (P0+P1)+(P2+P3)
            float s01 = racc[0] + racc[1], s23 = racc[2] + racc[3];
            float s45 = racc[4] + racc[5], s67 = racc[6] + racc[7];
            PL[lane][wv] = (s01 + s23) + (s45 + s67);
            __syncthreads();
            if (tid < 64) {
                float a01 = PL[tid][0] + PL[tid][1];
                float a23 = PL[tid][2] + PL[tid][3];
                rn_l[tid] = a01 + a23;
            }
            __syncthreads();
        }

        // prefetch next vt's first tile into buf0 (idle since kt=30)
        if (vt < 3) { loadB(vt + 1, 0); stageA(0, 0); writeB(0); }

        // fold: d = fl(fl(rn - 2M) + cn), first-min over ascending v
        #pragma unroll
        for (int j = 0; j < 8; j++) {
            const int v = vt * 256 + tx * 8 + j;
            const float cnv = cn[v];
            #pragma unroll
            for (int i = 0; i < 8; i++) {
                float m2 = 2.0f * acc[i][j];
                float t1 = rn_l[ty * 8 + i] - m2;
                float d  = t1 + cnv;
                if (d < best[i]) { best[i] = d; bidx[i] = v; }
            }
        }
    }

    // (min, argmin) butterfly with first-index tie rule
    #pragma unroll
    for (int i = 0; i < 8; i++) {
        float v = best[i]; int ix = bidx[i];
        #pragma unroll
        for (int m = 16; m >= 1; m >>= 1) {
            float ov = __shfl_xor(v, m, 64);
            int   oi = __shfl_xor(ix, m, 64);
            if (ov < v || (ov == v && oi < ix)) { v = ov; ix = oi; }
        }
        if (tx == 0) idx_l[ty * 8 + i] = ix;
    }
    __syncthreads();

    if (tid < 64) {
        int ix = idx_l[tid];
        idx_out[(size_t)(n0 + tid) * QQ + q] = (float)ix;
        atomicAdd(&hist[q * VQ + ix], 1);
    }

    // ---------- Phase 2: residual update + loss (+ final output) ----------
    float* c2 = &Bs[0][0][0];   // reuse as [64 rows][128 k] with XOR swizzle
    double lsum = 0.0;
    for (int kc = 0; kc < 4; kc++) {
        __syncthreads();
        {   // stage the selected code rows (coalesced 512B per row)
            int kk = tid & 127, r2 = tid >> 7;
            #pragma unroll
            for (int p = 0; p < 32; p++) {
                int rw = p * 2 + r2;
                const float* crow = cb + (size_t)idx_l[rw] * DQ + kc * 128;
                c2[rw * 128 + (kk ^ (rw & 31))] = crow[kk];
            }
        }
        __syncthreads();
        {
            #pragma unroll
            for (int w = 0; w < 32; w++) {
                int kk = wv * 32 + w;
                int k  = kc * 128 + kk;
                size_t o = ((size_t)b * DQ + k) * TQ + t0 + lane;
                float cv = c2[lane * 128 + (kk ^ (lane & 31))];
                float r_old = src[o];          // x at q==0, else stored residual
                float e  = r_old - cv;         // loss term (exact ref chain)
                lsum += (double)e * (double)e;
                float tt = cv - r_old;
                float qs = r_old + tt;         // quant_st, fp32 reference chain
                float rn2 = r_old - qs;        // updated residual
                if (q < QQ - 1) res[o] = rn2;
                else            res[o] = x[o] - rn2;   // quantized_out = x - r_final
            }
        }
    }
    #pragma unroll
    for (int m = 32; m >= 1; m >>= 1) lsum += __shfl_xor(lsum, m, 64);
    if ((tid & 63) == 0) redbuf[tid >> 6] = lsum;
    __syncthreads();
    if (tid == 0)
        atomicAdd(loss_acc + q, redbuf[0] + redbuf[1] + redbuf[2] + redbuf[3]);
}

// ---------------------------------------------------------------------------
// Scalars: usage%, loss, perplexity averaged over Q.
__global__ void finalize_kernel(const int* __restrict__ hist,
                                const double* __restrict__ loss_acc,
                                float* __restrict__ outs) {
    int lane = threadIdx.x;  // blockDim = 64
    float usage_sum = 0.f, perp_sum = 0.f;
    for (int q = 0; q < QQ; q++) {
        int nz = 0; float ent = 0.f;
        for (int v = lane; v < VQ; v += 64) {
            int c = hist[q * VQ + v];
            if (c > 0) {
                nz++;
                float p = (float)c / (float)NQ;
                ent += p * logf(p);
            }
        }
        #pragma unroll
        for (int m = 32; m >= 1; m >>= 1) {
            nz  += __shfl_xor(nz, m, 64);
            ent += __shfl_xor(ent, m, 64);
        }
        usage_sum += (float)nz / (float)VQ * 100.f;
        perp_sum  += expf(-ent);
    }
    if (lane == 0) {
        outs[0] = usage_sum / QQ;
        double ls = 0.0;
        for (int q = 0; q < QQ; q++)
            ls += loss_acc[q] * 1.25 / (double)NDQ;
        outs[1] = (float)(ls / QQ);
        outs[2] = perp_sum / QQ;
    }
}

// ---------------------------------------------------------------------------
extern "C" void kernel_launch(void* const* d_in, const int* in_sizes, int n_in,
                              void* d_out, int out_size, void* d_ws, size_t ws_size,
                              hipStream_t stream) {
    const float* x  = (const float*)d_in[0];
    const float* cb = (const float*)d_in[1];

    float* res     = (float*)d_out;          // [0, ND): residual -> quantized_out
    float* scal    = res + NDQ;              // usage, loss, perp
    float* idx_out = scal + 3;               // (B,T,Q) indices as float

    int*    hist     = (int*)d_ws;                                     // Q*V ints
    double* loss_acc = (double*)((char*)d_ws + QQ * VQ * sizeof(int)); // Q doubles
    float*  cn32     = (float*)(loss_acc + QQ);                        // Q*V floats

    hipMemsetAsync(d_ws, 0, QQ * VQ * sizeof(int) + QQ * sizeof(double), stream);

    cnorm32_kernel<<<(QQ * VQ) / 8, 256, 0, stream>>>(cb, cn32);

    for (int q = 0; q < QQ; q++) {
        vq32_pass<<<NQ / 64, 256, 0, stream>>>(x, cb, cn32, res, idx_out,
                                               hist, loss_acc, q);
    }

    finalize_kernel<<<1, 64, 0, stream>>>(hist, loss_acc, scal);
}

// Round 9
// 9485.197 us; speedup vs baseline: 12.8820x; 1.1031x over previous
//
#include <hip/hip_runtime.h>
#include <math.h>

// Problem constants (fixed by the reference)
#define BQ 32
#define DQ 512
#define TQ 2048
#define VQ 1024
#define QQ 6
#define NQ (BQ * TQ)                 // 65536 rows
#define NDQ ((size_t)NQ * DQ)        // 33,554,432 elements

// ---------------------------------------------------------------------------
// B-tile LDS swizzle (layout only; values untouched)
__device__ __forceinline__ int bswz(int kk, int vv) {
    return vv ^ ((((kk & 7) ^ ((vv >> 5) & 7))) << 2);
}

// ---------------------------------------------------------------------------
// numpy-pairwise fp32 ||c||^2: per 512-row = (P0+P1)+(P2+P3), each P = 128-block
// with 8 accumulators + ((r0+r1)+(r2+r3))+((r4+r5)+(r6+r7)) tree. 32 lanes/code.
__global__ void cnorm32_kernel(const float* __restrict__ cb, float* __restrict__ cn) {
    #pragma clang fp contract(off)
    int gw   = (blockIdx.x * blockDim.x + threadIdx.x) >> 5;  // 32-lane group
    int l    = threadIdx.x & 31;
    if (gw >= QQ * VQ) return;
    const float* row = cb + (size_t)gw * DQ;
    const int c = l >> 3, j = l & 7;
    float acc = 0.f;
    #pragma unroll
    for (int m = 0; m < 16; m++) {
        float v = row[c * 128 + m * 8 + j];
        float a = v * v;          // separate fp32 round (numpy temp array)
        acc = acc + a;            // sequential ascending m
    }
    float s = acc + __shfl_xor(acc, 1, 64);   // (r0+r1) etc.
    s = s + __shfl_xor(s, 2, 64);             // +(r2+r3) pair
    s = s + __shfl_xor(s, 4, 64);             // full 8-tree -> Pc
    float t = s + __shfl_xor(s, 8, 64);       // (P0+P1), (P2+P3)
    t = t + __shfl_xor(t, 16, 64);            // (P0+P1)+(P2+P3)
    if (l == 0) cn[gw] = t;
}

// ---------------------------------------------------------------------------
// One residual-VQ stage, fp32 numpy-replicated index pipeline.
// 64 rows x 256 codes per block, BK=16, 8x8 micro-tile (1.0 B/lane/FMA),
// reg-staged double-buffered pipeline (issue-early / write-late).
// A: [2][16][64] = SM[0,2048). B: [2][16][256] = SM[2048,10240).
#define AS(bf,kk,r)  SM[(bf)*1024 + (kk)*64 + (r)]
#define BS(bf,kk,c)  SM[2048 + (bf)*4096 + (kk)*256 + (c)]

__global__ __launch_bounds__(256) void vq32_pass(
    const float* __restrict__ x, const float* __restrict__ cb_all,
    const float* __restrict__ cn_all,
    float* __restrict__ res,       // d_out base; residual chain, final: quantized
    float* __restrict__ idx_out,   // d_out + ND + 3, (B,T,Q) as float
    int* __restrict__ hist, double* __restrict__ loss_acc, int q)
{
    #pragma clang fp contract(off)
    __shared__ float SM[10240];         // 40 KiB: A(8K) + B(32K); ph2 c2 = B region
    __shared__ int   idx_l[64];
    __shared__ float PL[64][4];
    __shared__ float rn_l[64];
    __shared__ double redbuf[4];

    const int tid = threadIdx.x;
    const int n0  = blockIdx.x * 64;
    const int b   = n0 / TQ;
    const int t0  = n0 % TQ;
    const float* cb  = cb_all + (size_t)q * VQ * DQ;
    const float* cn  = cn_all + q * VQ;
    const float* src = (q == 0) ? x : res;

    const int rr  = tid & 63;           // A staging row / rn row / phase-2 row
    const int kq  = tid >> 6;           // A staging k-quarter (4 k's)
    const int kks = tid & 15;           // B staging: k
    const int vbs = tid >> 4;           // B staging: code subgroup (16 codes)
    const int ty  = tid >> 5;           // compute: 8 row groups x 8 rows
    const int tx  = tid & 31;           // compute: 32 code groups x 8 codes

    float aR[4], bR[16];

    auto loadA = [&](int kt) {
        const float* sp = src + ((size_t)b * DQ + kt * 16 + kq * 4) * TQ + t0 + rr;
        #pragma unroll
        for (int u = 0; u < 4; u++) aR[u] = sp[(size_t)u * TQ];
    };
    auto loadB = [&](int vt, int kt) {
        const float* bp = cb + (size_t)(vt * 256 + vbs * 16) * DQ + kt * 16 + kks;
        #pragma unroll
        for (int w = 0; w < 16; w++) bR[w] = bp[(size_t)w * DQ];
    };
    auto writeA = [&](int bf) {
        #pragma unroll
        for (int u = 0; u < 4; u++) AS(bf, kq * 4 + u, rr) = aR[u];
    };
    auto writeB = [&](int bf) {
        #pragma unroll
        for (int w = 0; w < 16; w++) BS(bf, kks, bswz(kks, vbs * 16 + w)) = bR[w];
    };

    float racc[8];
    #pragma unroll
    for (int j = 0; j < 8; j++) racc[j] = 0.f;

    float best[8]; int bidx[8];
    #pragma unroll
    for (int i = 0; i < 8; i++) { best[i] = INFINITY; bidx[i] = 0; }

    // prologue: stage (vt=0, kt=0) into buffer 0
    loadA(0); loadB(0, 0);
    writeA(0); writeB(0);

    for (int vt = 0; vt < 4; vt++) {
        float acc[8][8];
        #pragma unroll
        for (int i = 0; i < 8; i++)
            #pragma unroll
            for (int j = 0; j < 8; j++) acc[i][j] = 0.f;

        int cur = 0;
        for (int kt = 0; kt < 32; kt++) {
            if (kt < 31) { loadA(kt + 1); loadB(vt, kt + 1); }   // issue early
            __syncthreads();                                     // buf[cur] ready
            // strict ascending-k fp32 FMA chain per (row,code) — BLAS order
            #pragma unroll
            for (int kk = 0; kk < 16; kk++) {
                const float4 a0 = *(const float4*)&AS(cur, kk, ty * 8);
                const float4 a1 = *(const float4*)&AS(cur, kk, ty * 8 + 4);
                const float4 b0 = *(const float4*)&BS(cur, kk, bswz(kk, tx * 8));
                const float4 b1 = *(const float4*)&BS(cur, kk, bswz(kk, tx * 8 + 4));
                const float av[8] = {a0.x,a0.y,a0.z,a0.w, a1.x,a1.y,a1.z,a1.w};
                const float bv[8] = {b0.x,b0.y,b0.z,b0.w, b1.x,b1.y,b1.z,b1.w};
                #pragma unroll
                for (int i = 0; i < 8; i++)
                    #pragma unroll
                    for (int j = 0; j < 8; j++)
                        acc[i][j] = fmaf(av[i], bv[j], acc[i][j]);
            }
            if (kt < 31) { writeA(cur ^ 1); writeB(cur ^ 1); }   // write late
            // merged rn pass (vt==0): row-per-thread, numpy 128-chunk order:
            // within-chunk index mm*8+j2, mm = (kt&7)*2 + mmh ascending
            if (vt == 0 && tid < 64) {
                #pragma unroll
                for (int mmh = 0; mmh < 2; mmh++)
                    #pragma unroll
                    for (int j2 = 0; j2 < 8; j2++) {
                        float v  = AS(cur, mmh * 8 + j2, rr);
                        float a2 = v * v;
                        racc[j2] = racc[j2] + a2;
                    }
                if ((kt & 7) == 7) {       // chunk end: 8-acc pairwise tree
                    float s01 = racc[0] + racc[1], s23 = racc[2] + racc[3];
                    float s45 = racc[4] + racc[5], s67 = racc[6] + racc[7];
                    PL[rr][kt >> 3] = (s01 + s23) + (s45 + s67);
                    #pragma unroll
                    for (int j2 = 0; j2 < 8; j2++) racc[j2] = 0.f;
                }
            }
            cur ^= 1;
        }

        if (vt == 0) {
            if (tid < 64) {     // same-thread PL -> rn_l, then publish
                float a01 = PL[tid][0] + PL[tid][1];
                float a23 = PL[tid][2] + PL[tid][3];
                rn_l[tid] = a01 + a23;
            }
            __syncthreads();
        }

        // prefetch next vt's first tile into buf0 (idle since kt=30)
        if (vt < 3) { loadA(0); loadB(vt + 1, 0); }

        // fold: d = fl(fl(rn - 2M) + cn), first-min over ascending v
        #pragma unroll
        for (int j = 0; j < 8; j++) {
            const int v = vt * 256 + tx * 8 + j;
            const float cnv = cn[v];
            #pragma unroll
            for (int i = 0; i < 8; i++) {
                float m2 = 2.0f * acc[i][j];
                float t1 = rn_l[ty * 8 + i] - m2;
                float d  = t1 + cnv;
                if (d < best[i]) { best[i] = d; bidx[i] = v; }
            }
        }

        if (vt < 3) { writeA(0); writeB(0); }
    }

    // (min, argmin) butterfly with first-index tie rule
    #pragma unroll
    for (int i = 0; i < 8; i++) {
        float v = best[i]; int ix = bidx[i];
        #pragma unroll
        for (int m = 16; m >= 1; m >>= 1) {
            float ov = __shfl_xor(v, m, 64);
            int   oi = __shfl_xor(ix, m, 64);
            if (ov < v || (ov == v && oi < ix)) { v = ov; ix = oi; }
        }
        if (tx == 0) idx_l[ty * 8 + i] = ix;
    }
    __syncthreads();

    if (tid < 64) {
        int ix = idx_l[tid];
        idx_out[(size_t)(n0 + tid) * QQ + q] = (float)ix;
        atomicAdd(&hist[q * VQ + ix], 1);
    }

    // ---------- Phase 2: residual update + loss (+ final output) ----------
    float* c2 = &SM[2048];   // reuse B region as [64 rows][128 k], XOR swizzle
    double lsum = 0.0;
    for (int kc = 0; kc < 4; kc++) {
        __syncthreads();
        {   // stage the selected code rows (coalesced 512B per row)
            int kk = tid & 127, r2 = tid >> 7;
            #pragma unroll
            for (int p = 0; p < 32; p++) {
                int rw = p * 2 + r2;
                const float* crow = cb + (size_t)idx_l[rw] * DQ + kc * 128;
                c2[rw * 128 + (kk ^ (rw & 31))] = crow[kk];
            }
        }
        __syncthreads();
        {
            int kb = tid >> 6;   // 0..3 : 32 k's each
            #pragma unroll
            for (int w = 0; w < 32; w++) {
                int kk = kb * 32 + w;
                int k  = kc * 128 + kk;
                size_t o = ((size_t)b * DQ + k) * TQ + t0 + rr;
                float cv = c2[rr * 128 + (kk ^ (rr & 31))];
                float r_old = src[o];          // x at q==0, else stored residual
                float e  = r_old - cv;         // loss term (exact ref chain)
                lsum += (double)e * (double)e;
                float tt = cv - r_old;
                float qs = r_old + tt;         // quant_st, fp32 reference chain
                float rn2 = r_old - qs;        // updated residual
                if (q < QQ - 1) res[o] = rn2;
                else            res[o] = x[o] - rn2;   // quantized_out = x - r_final
            }
        }
    }
    #pragma unroll
    for (int m = 32; m >= 1; m >>= 1) lsum += __shfl_xor(lsum, m, 64);
    if ((tid & 63) == 0) redbuf[tid >> 6] = lsum;
    __syncthreads();
    if (tid == 0)
        atomicAdd(loss_acc + q, redbuf[0] + redbuf[1] + redbuf[2] + redbuf[3]);
}

// ---------------------------------------------------------------------------
// Scalars: usage%, loss, perplexity averaged over Q.
__global__ void finalize_kernel(const int* __restrict__ hist,
                                const double* __restrict__ loss_acc,
                                float* __restrict__ outs) {
    int lane = threadIdx.x;  // blockDim = 64
    float usage_sum = 0.f, perp_sum = 0.f;
    for (int q = 0; q < QQ; q++) {
        int nz = 0; float ent = 0.f;
        for (int v = lane; v < VQ; v += 64) {
            int c = hist[q * VQ + v];
            if (c > 0) {
                nz++;
                float p = (float)c / (float)NQ;
                ent += p * logf(p);
            }
        }
        #pragma unroll
        for (int m = 32; m >= 1; m >>= 1) {
            nz  += __shfl_xor(nz, m, 64);
            ent += __shfl_xor(ent, m, 64);
        }
        usage_sum += (float)nz / (float)VQ * 100.f;
        perp_sum  += expf(-ent);
    }
    if (lane == 0) {
        outs[0] = usage_sum / QQ;
        double ls = 0.0;
        for (int q = 0; q < QQ; q++)
            ls += loss_acc[q] * 1.25 / (double)NDQ;
        outs[1] = (float)(ls / QQ);
        outs[2] = perp_sum / QQ;
    }
}

// ---------------------------------------------------------------------------
extern "C" void kernel_launch(void* const* d_in, const int* in_sizes, int n_in,
                              void* d_out, int out_size, void* d_ws, size_t ws_size,
                              hipStream_t stream) {
    const float* x  = (const float*)d_in[0];
    const float* cb = (const float*)d_in[1];

    float* res     = (float*)d_out;          // [0, ND): residual -> quantized_out
    float* scal    = res + NDQ;              // usage, loss, perp
    float* idx_out = scal + 3;               // (B,T,Q) indices as float

    int*    hist     = (int*)d_ws;                                     // Q*V ints
    double* loss_acc = (double*)((char*)d_ws + QQ * VQ * sizeof(int)); // Q doubles
    float*  cn32     = (float*)(loss_acc + QQ);                        // Q*V floats

    hipMemsetAsync(d_ws, 0, QQ * VQ * sizeof(int) + QQ * sizeof(double), stream);

    cnorm32_kernel<<<(QQ * VQ) / 8, 256, 0, stream>>>(cb, cn32);

    for (int q = 0; q < QQ; q++) {
        vq32_pass<<<NQ / 64, 256, 0, stream>>>(x, cb, cn32, res, idx_out,
                                               hist, loss_acc, q);
    }

    finalize_kernel<<<1, 64, 0, stream>>>(hist, loss_acc, scal);
}

// Round 11
// 6543.833 us; speedup vs baseline: 18.6723x; 1.4495x over previous
//
#include <hip/hip_runtime.h>
#include <math.h>

// Problem constants (fixed by the reference)
#define BQ 32
#define DQ 512
#define TQ 2048
#define VQ 1024
#define QQ 6
#define NQ (BQ * TQ)                 // 65536 rows
#define NDQ ((size_t)NQ * DQ)        // 33,554,432 elements

#define EPS_TIE 1.5f    // bf16-dot near-tie margin (~10 sigma incl. stage-5 norms)

typedef __attribute__((ext_vector_type(8))) short short8;   // 8 bf16 (4 VGPR)
typedef __attribute__((ext_vector_type(4))) float f32x4;    // MFMA acc

union FragU { ushort4 h[2]; short8 v; };

// fp32 -> bf16 RNE (bit trick; exactness of this rounding is NOT relied upon)
__device__ __forceinline__ ushort f2bf(float f) {
    unsigned u = __float_as_uint(f);
    return (ushort)((u + 0x7FFFu + ((u >> 16) & 1u)) >> 16);
}

// B-tile LDS swizzle (layout only; values untouched) — fallback path
__device__ __forceinline__ int bswz(int kk, int vv) {
    return vv ^ ((((kk & 7) ^ ((vv >> 5) & 7))) << 2);
}

// ---------------------------------------------------------------------------
// numpy-pairwise fp32 ||c||^2 (proven bit-exact): per 512-row =
// (P0+P1)+(P2+P3); each P = 128-block, 8 accs ascending m + pairwise tree.
__global__ void cnorm32_kernel(const float* __restrict__ cb, float* __restrict__ cn) {
    #pragma clang fp contract(off)
    int gw = (blockIdx.x * blockDim.x + threadIdx.x) >> 5;
    int l  = threadIdx.x & 31;
    if (gw >= QQ * VQ) return;
    const float* row = cb + (size_t)gw * DQ;
    const int c = l >> 3, j = l & 7;
    float acc = 0.f;
    #pragma unroll
    for (int m = 0; m < 16; m++) {
        float v = row[c * 128 + m * 8 + j];
        float a = v * v;
        acc = acc + a;
    }
    float s = acc + __shfl_xor(acc, 1, 64);
    s = s + __shfl_xor(s, 2, 64);
    s = s + __shfl_xor(s, 4, 64);
    float t = s + __shfl_xor(s, 8, 64);
    t = t + __shfl_xor(t, 16, 64);
    if (l == 0) cn[gw] = t;
}

// ===========================================================================
// FAST PATH kernels
// ===========================================================================

// Stage q candidate pass: bf16 MFMA distance-estimate GEMM + per-row top-2.
__global__ __launch_bounds__(512) void mfma_pass(
    const float* __restrict__ src, const float* __restrict__ cb_all,
    const float* __restrict__ cn_all,
    float* __restrict__ idx_out, int* __restrict__ nflag,
    int* __restrict__ flag_list, int q)
{
    __shared__ ushort As[2][128][36];   // 18 KiB  [t][k] bf16
    __shared__ ushort Bs[2][256][36];   // 36 KiB  [code][k] bf16
    __shared__ float  cn_l[256];
    __shared__ float  M1[128][4];
    __shared__ float  M2[128][4];
    __shared__ int    MI[128][4];

    const int tid = threadIdx.x;
    const int n0  = blockIdx.x * 128;
    const int b   = n0 / TQ;
    const int t0  = n0 % TQ;
    const float* cb = cb_all + (size_t)q * VQ * DQ;
    const float* cn = cn_all + q * VQ;

    const int wv = tid >> 6, l = tid & 63;
    const int wrow = (wv >> 2) * 64;      // 2 row-waves
    const int wcol = (wv & 3) * 64;       // 4 col-waves
    const int lr = l & 15, lk = l >> 4;   // frag lane decomposition

    const bool isA = (wv < 4);
    const int a_tg = tid & 31;
    const int a_kg = (tid >> 5) & 7;
    const int b_c  = tid - 256;

    float4 aR4[4];
    float4 bR4[8];

    auto loadA = [&](int kt) {
        if (isA) {
            #pragma unroll
            for (int u = 0; u < 4; u++)
                aR4[u] = *(const float4*)&src[((size_t)(b * DQ + kt * 32 + a_kg * 4 + u)) * TQ + t0 + a_tg * 4];
        }
    };
    auto writeA = [&](int bf) {
        if (isA) {
            #pragma unroll
            for (int i = 0; i < 4; i++) {
                ushort4 w;
                w.x = f2bf(((const float*)&aR4[0])[i]);
                w.y = f2bf(((const float*)&aR4[1])[i]);
                w.z = f2bf(((const float*)&aR4[2])[i]);
                w.w = f2bf(((const float*)&aR4[3])[i]);
                *(ushort4*)&As[bf][a_tg * 4 + i][a_kg * 4] = w;
            }
        }
    };
    auto loadB = [&](int vt, int kt) {
        if (!isA) {
            const float* bp = cb + (size_t)(vt * 256 + b_c) * DQ + kt * 32;
            #pragma unroll
            for (int u = 0; u < 8; u++) bR4[u] = *(const float4*)&bp[u * 4];
        }
    };
    auto writeB = [&](int bf) {
        if (!isA) {
            #pragma unroll
            for (int u = 0; u < 8; u++) {
                ushort4 w;
                w.x = f2bf(bR4[u].x); w.y = f2bf(bR4[u].y);
                w.z = f2bf(bR4[u].z); w.w = f2bf(bR4[u].w);
                *(ushort4*)&Bs[bf][b_c][u * 4] = w;
            }
        }
    };

    float tb1[16], tb2[16]; int ti1[16];
    #pragma unroll
    for (int i = 0; i < 16; i++) { tb1[i] = INFINITY; tb2[i] = INFINITY; ti1[i] = 0; }

    loadA(0); loadB(0, 0);
    writeA(0); writeB(0);

    for (int vt = 0; vt < 4; vt++) {
        __syncthreads();
        if (tid < 256) cn_l[tid] = cn[vt * 256 + tid];

        f32x4 acc[4][4];
        #pragma unroll
        for (int rt = 0; rt < 4; rt++)
            #pragma unroll
            for (int ct = 0; ct < 4; ct++) {
                f32x4 z = {0.f, 0.f, 0.f, 0.f};
                acc[rt][ct] = z;
            }

        int cur = 0;
        for (int kt = 0; kt < 16; kt++) {
            if (kt < 15) { loadA(kt + 1); loadB(vt, kt + 1); }
            __syncthreads();
            FragU fa[4], fb[4];
            #pragma unroll
            for (int rt = 0; rt < 4; rt++) {
                const int t = wrow + rt * 16 + lr;
                fa[rt].h[0] = *(const ushort4*)&As[cur][t][lk * 8];
                fa[rt].h[1] = *(const ushort4*)&As[cur][t][lk * 8 + 4];
            }
            #pragma unroll
            for (int ct = 0; ct < 4; ct++) {
                const int c = wcol + ct * 16 + lr;
                fb[ct].h[0] = *(const ushort4*)&Bs[cur][c][lk * 8];
                fb[ct].h[1] = *(const ushort4*)&Bs[cur][c][lk * 8 + 4];
            }
            #pragma unroll
            for (int rt = 0; rt < 4; rt++)
                #pragma unroll
                for (int ct = 0; ct < 4; ct++)
                    acc[rt][ct] = __builtin_amdgcn_mfma_f32_16x16x32_bf16(
                        fa[rt].v, fb[ct].v, acc[rt][ct], 0, 0, 0);
            if (kt < 15) { writeA(cur ^ 1); writeB(cur ^ 1); }
            cur ^= 1;
        }

        // fold acc -> per-lane top-2 (est = cn - 2*dot)
        #pragma unroll
        for (int ct = 0; ct < 4; ct++) {
            const int cl = wcol + ct * 16 + lr;
            const float cnv = cn_l[cl];
            const int c = vt * 256 + cl;
            #pragma unroll
            for (int rt = 0; rt < 4; rt++)
                #pragma unroll
                for (int r = 0; r < 4; r++) {
                    float est = fmaf(-2.f, acc[rt][ct][r], cnv);
                    const int s = rt * 4 + r;
                    bool w = (est < tb1[s]) || (est == tb1[s] && c < ti1[s]);
                    float loser = w ? tb1[s] : est;
                    if (w) { tb1[s] = est; ti1[s] = c; }
                    tb2[s] = fminf(tb2[s], loser);
                }
        }

        if (vt < 3) { loadA(0); loadB(vt + 1, 0); writeA(0); writeB(0); }
    }

    // merge top-2 across the 16 col-lanes (lr), keeping idx tie rule
    #pragma unroll
    for (int s = 0; s < 16; s++) {
        float b1 = tb1[s], b2 = tb2[s]; int i1 = ti1[s];
        #pragma unroll
        for (int m = 1; m <= 8; m <<= 1) {
            float ob1 = __shfl_xor(b1, m, 64);
            int   oi1 = __shfl_xor(i1, m, 64);
            float ob2 = __shfl_xor(b2, m, 64);
            b2 = fminf(b2, ob2);
            bool w = (ob1 < b1) || (ob1 == b1 && oi1 < i1);
            float loser = w ? b1 : ob1;
            if (w) { b1 = ob1; i1 = oi1; }
            b2 = fminf(b2, loser);
        }
        if (lr == 0) {
            int rowl = wrow + (s >> 2) * 16 + lk * 4 + (s & 3);
            M1[rowl][wv & 3] = b1;
            M2[rowl][wv & 3] = b2;
            MI[rowl][wv & 3] = i1;
        }
    }
    __syncthreads();

    if (tid < 128) {
        float b1 = M1[tid][0], b2 = M2[tid][0]; int i1 = MI[tid][0];
        #pragma unroll
        for (int j2 = 1; j2 < 4; j2++) {
            float ob1 = M1[tid][j2], ob2 = M2[tid][j2]; int oi1 = MI[tid][j2];
            b2 = fminf(b2, ob2);
            bool w = (ob1 < b1) || (ob1 == b1 && oi1 < i1);
            float loser = w ? b1 : ob1;
            if (w) { b1 = ob1; i1 = oi1; }
            b2 = fminf(b2, loser);
        }
        const int n = n0 + tid;
        idx_out[(size_t)n * QQ + q] = (float)i1;
        if (b2 - b1 < EPS_TIE) {
            int slot = atomicAdd(&nflag[q], 1);
            flag_list[slot] = n;
        }
    }
}

// ---------------------------------------------------------------------------
// Exact numpy-fp32 re-resolution of flagged rows: full 1024-code scan with the
// PROVEN bit-exact recipe.
__global__ __launch_bounds__(256) void refine_pass(
    const float* __restrict__ src, const float* __restrict__ cb_all,
    const float* __restrict__ cn_all, float* __restrict__ idx_out,
    const int* __restrict__ nflag, const int* __restrict__ flag_list, int q)
{
    #pragma clang fp contract(off)
    __shared__ float rL[16][520];
    __shared__ float cbL[128][33];
    __shared__ float rnL[16];
    __shared__ int   rowid[16];

    const int tid = threadIdx.x;
    const float* cb = cb_all + (size_t)q * VQ * DQ;
    const float* cn = cn_all + q * VQ;
    const int total = nflag[q];

    for (int base = blockIdx.x * 16; base < total; base += gridDim.x * 16) {
        if (tid < 16) {
            int ii = base + tid;
            if (ii > total - 1) ii = total - 1;
            rowid[tid] = flag_list[ii];
        }
        __syncthreads();
        {
            const int row = tid & 15, kg = tid >> 4;
            const int n = rowid[row];
            const int bb = n / TQ, tt = n % TQ;
            for (int u = 0; u < 32; u++)
                rL[row][kg * 32 + u] = src[((size_t)(bb * DQ + kg * 32 + u)) * TQ + tt];
        }
        __syncthreads();
        if (tid < 16) {
            float P[4];
            #pragma unroll
            for (int c4 = 0; c4 < 4; c4++) {
                float r8[8];
                #pragma unroll
                for (int j = 0; j < 8; j++) r8[j] = 0.f;
                for (int m = 0; m < 16; m++)
                    #pragma unroll
                    for (int j = 0; j < 8; j++) {
                        float v = rL[tid][c4 * 128 + m * 8 + j];
                        float a = v * v;
                        r8[j] = r8[j] + a;
                    }
                float s01 = r8[0] + r8[1], s23 = r8[2] + r8[3];
                float s45 = r8[4] + r8[5], s67 = r8[6] + r8[7];
                P[c4] = (s01 + s23) + (s45 + s67);
            }
            rnL[tid] = (P[0] + P[1]) + (P[2] + P[3]);
        }

        const int row = tid >> 4, tix = tid & 15;
        float bv = INFINITY; int bi = 0;

        for (int ct = 0; ct < 8; ct++) {
            float acc8[8];
            #pragma unroll
            for (int j = 0; j < 8; j++) acc8[j] = 0.f;
            for (int kt = 0; kt < 16; kt++) {
                __syncthreads();
                {
                    const int cc = tid >> 1, half = tid & 1;
                    const float* bp = cb + (size_t)(ct * 128 + cc) * DQ + kt * 32 + half * 16;
                    #pragma unroll
                    for (int u = 0; u < 4; u++) {
                        float4 f = *(const float4*)&bp[u * 4];
                        cbL[cc][half * 16 + u * 4 + 0] = f.x;
                        cbL[cc][half * 16 + u * 4 + 1] = f.y;
                        cbL[cc][half * 16 + u * 4 + 2] = f.z;
                        cbL[cc][half * 16 + u * 4 + 3] = f.w;
                    }
                }
                __syncthreads();
                #pragma unroll
                for (int k = 0; k < 32; k++) {
                    float rv = rL[row][kt * 32 + k];
                    #pragma unroll
                    for (int j = 0; j < 8; j++)
                        acc8[j] = fmaf(rv, cbL[tix + 16 * j][k], acc8[j]);
                }
            }
            #pragma unroll
            for (int j = 0; j < 8; j++) {
                const int c = ct * 128 + tix + 16 * j;
                float m2 = 2.0f * acc8[j];
                float t1 = rnL[row] - m2;
                float d  = t1 + cn[c];
                if (d < bv) { bv = d; bi = c; }
            }
        }
        #pragma unroll
        for (int m = 1; m <= 8; m <<= 1) {
            float ov = __shfl_xor(bv, m, 64);
            int   oi = __shfl_xor(bi, m, 64);
            if (ov < bv || (ov == bv && oi < bi)) { bv = ov; bi = oi; }
        }
        if (tix == 0 && base + row < total) {
            const int n = rowid[row];
            idx_out[(size_t)n * QQ + q] = (float)bi;
        }
        __syncthreads();
    }
}

// ---------------------------------------------------------------------------
// Residual update + loss + hist (+ final output at q==Q-1). Proven chain.
__global__ __launch_bounds__(256) void phase2_pass(
    const float* __restrict__ x, const float* __restrict__ cb_all,
    const float* __restrict__ src, float* __restrict__ res,
    const float* __restrict__ idx_out, int* __restrict__ hist,
    double* __restrict__ loss_acc, int q)
{
    #pragma clang fp contract(off)
    __shared__ float c2[64 * 128];
    __shared__ int   idx_l[64];
    __shared__ double redbuf[4];

    const int tid = threadIdx.x;
    const int n0  = blockIdx.x * 64;
    const int b   = n0 / TQ;
    const int t0  = n0 % TQ;
    const float* cb = cb_all + (size_t)q * VQ * DQ;
    const int rr = tid & 63;

    if (tid < 64) idx_l[tid] = (int)idx_out[(size_t)(n0 + tid) * QQ + q];
    __syncthreads();
    if (tid < 64) atomicAdd(&hist[q * VQ + idx_l[tid]], 1);

    double lsum = 0.0;
    for (int kc = 0; kc < 4; kc++) {
        __syncthreads();
        {
            int kk = tid & 127, r2 = tid >> 7;
            #pragma unroll
            for (int p = 0; p < 32; p++) {
                int rw = p * 2 + r2;
                const float* crow = cb + (size_t)idx_l[rw] * DQ + kc * 128;
                c2[rw * 128 + (kk ^ (rw & 31))] = crow[kk];
            }
        }
        __syncthreads();
        {
            int kb = tid >> 6;
            #pragma unroll
            for (int w = 0; w < 32; w++) {
                int kk = kb * 32 + w;
                int k  = kc * 128 + kk;
                size_t o = ((size_t)b * DQ + k) * TQ + t0 + rr;
                float cv = c2[rr * 128 + (kk ^ (rr & 31))];
                float r_old = src[o];
                float e  = r_old - cv;
                lsum += (double)e * (double)e;
                float tt = cv - r_old;
                float qs = r_old + tt;
                float rn2 = r_old - qs;
                if (q < QQ - 1) res[o] = rn2;
                else            res[o] = x[o] - rn2;
            }
        }
    }
    #pragma unroll
    for (int m = 32; m >= 1; m >>= 1) lsum += __shfl_xor(lsum, m, 64);
    if ((tid & 63) == 0) redbuf[tid >> 6] = lsum;
    __syncthreads();
    if (tid == 0)
        atomicAdd(loss_acc + q, redbuf[0] + redbuf[1] + redbuf[2] + redbuf[3]);
}

// ===========================================================================
// FALLBACK: round-6 proven all-fp32 stage kernel (bit-exact, ~1.3 ms/stage)
// ===========================================================================
__global__ __launch_bounds__(256) void vq32_fallback(
    const float* __restrict__ x, const float* __restrict__ cb_all,
    const float* __restrict__ cn_all,
    float* __restrict__ res, float* __restrict__ idx_out,
    int* __restrict__ hist, double* __restrict__ loss_acc, int q)
{
    #pragma clang fp contract(off)
    __shared__ float As[2][32][64];
    __shared__ float Bs[2][32][128];
    __shared__ int   idx_l[64];
    __shared__ float PL[64][4];
    __shared__ float rn_l[64];
    __shared__ double redbuf[4];

    const int tid = threadIdx.x;
    const int n0  = blockIdx.x * 64;
    const int b   = n0 / TQ;
    const int t0  = n0 % TQ;
    const float* cb  = cb_all + (size_t)q * VQ * DQ;
    const float* cn  = cn_all + q * VQ;
    const float* src = (q == 0) ? x : res;

    const int rr  = tid & 63;
    const int kkb = tid >> 6;
    const int kks = tid & 31;
    const int vbs = tid >> 5;
    const int ty  = tid >> 5;
    const int tx  = tid & 31;

    float aR[8], bR[16];

    auto loadA = [&](int kt) {
        const float* sp = src + ((size_t)b * DQ + kt * 32) * TQ + t0 + rr;
        #pragma unroll
        for (int u = 0; u < 8; u++) aR[u] = sp[(size_t)(kkb * 8 + u) * TQ];
    };
    auto loadB = [&](int vt, int kt) {
        const float* bp = cb + (size_t)(vt * 128 + vbs * 16) * DQ + kt * 32 + kks;
        #pragma unroll
        for (int w = 0; w < 16; w++) bR[w] = bp[(size_t)w * DQ];
    };
    auto writeA = [&](int bf) {
        #pragma unroll
        for (int u = 0; u < 8; u++) As[bf][kkb * 8 + u][rr] = aR[u];
    };
    auto writeB = [&](int bf) {
        #pragma unroll
        for (int w = 0; w < 16; w++) Bs[bf][kks][bswz(kks, vbs * 16 + w)] = bR[w];
    };

    float racc[8];
    #pragma unroll
    for (int j = 0; j < 8; j++) racc[j] = 0.f;

    float best[8]; int bidx[8];
    #pragma unroll
    for (int i = 0; i < 8; i++) { best[i] = INFINITY; bidx[i] = 0; }

    loadA(0); loadB(0, 0);
    writeA(0); writeB(0);

    for (int vt = 0; vt < 8; vt++) {
        float acc[8][4];
        #pragma unroll
        for (int i = 0; i < 8; i++)
            #pragma unroll
            for (int j = 0; j < 4; j++) acc[i][j] = 0.f;

        int cur = 0;
        for (int kt = 0; kt < 16; kt++) {
            if (kt < 15) { loadA(kt + 1); loadB(vt, kt + 1); }
            __syncthreads();
            for (int kk = 0; kk < 32; kk++) {
                const float4 a0 = *(const float4*)&As[cur][kk][ty * 8];
                const float4 a1 = *(const float4*)&As[cur][kk][ty * 8 + 4];
                const float4 b0 = *(const float4*)&Bs[cur][kk][bswz(kk, tx * 4)];
                const float av[8] = {a0.x,a0.y,a0.z,a0.w,a1.x,a1.y,a1.z,a1.w};
                const float bv[4] = {b0.x,b0.y,b0.z,b0.w};
                #pragma unroll
                for (int i = 0; i < 8; i++)
                    #pragma unroll
                    for (int j = 0; j < 4; j++)
                        acc[i][j] = fmaf(av[i], bv[j], acc[i][j]);
            }
            if (vt == 0 && (kt >> 2) == kkb) {
                #pragma unroll
                for (int mm = 0; mm < 4; mm++)
                    #pragma unroll
                    for (int j2 = 0; j2 < 8; j2++) {
                        float v = As[cur][mm * 8 + j2][rr];
                        float a2 = v * v;
                        racc[j2] = racc[j2] + a2;
                    }
            }
            if (kt < 15) { writeA(cur ^ 1); writeB(cur ^ 1); }
            cur ^= 1;
        }

        if (vt == 0) {
            float s01 = racc[0] + racc[1], s23 = racc[2] + racc[3];
            float s45 = racc[4] + racc[5], s67 = racc[6] + racc[7];
            PL[rr][kkb] = (s01 + s23) + (s45 + s67);
            __syncthreads();
            if (tid < 64) {
                float a01 = PL[tid][0] + PL[tid][1];
                float a23 = PL[tid][2] + PL[tid][3];
                rn_l[tid] = a01 + a23;
            }
            __syncthreads();
        }

        if (vt < 7) { loadA(0); loadB(vt + 1, 0); }

        #pragma unroll
        for (int j = 0; j < 4; j++) {
            const int v = vt * 128 + tx * 4 + j;
            const float cnv = cn[v];
            #pragma unroll
            for (int i = 0; i < 8; i++) {
                float m2 = 2.0f * acc[i][j];
                float t1 = rn_l[ty * 8 + i] - m2;
                float d  = t1 + cnv;
                if (d < best[i]) { best[i] = d; bidx[i] = v; }
            }
        }

        if (vt < 7) { writeA(0); writeB(0); }
    }

    #pragma unroll
    for (int i = 0; i < 8; i++) {
        float v = best[i]; int ix = bidx[i];
        #pragma unroll
        for (int m = 16; m >= 1; m >>= 1) {
            float ov = __shfl_xor(v, m, 64);
            int   oi = __shfl_xor(ix, m, 64);
            if (ov < v || (ov == v && oi < ix)) { v = ov; ix = oi; }
        }
        if (tx == 0) idx_l[ty * 8 + i] = ix;
    }
    __syncthreads();

    if (tid < 64) {
        int ix = idx_l[tid];
        idx_out[(size_t)(n0 + tid) * QQ + q] = (float)ix;
        atomicAdd(&hist[q * VQ + ix], 1);
    }

    float* c2 = &Bs[0][0][0];
    double lsum = 0.0;
    for (int kc = 0; kc < 4; kc++) {
        __syncthreads();
        {
            int kk = tid & 127, r2 = tid >> 7;
            #pragma unroll
            for (int p = 0; p < 32; p++) {
                int rw = p * 2 + r2;
                const float* crow = cb + (size_t)idx_l[rw] * DQ + kc * 128;
                c2[rw * 128 + (kk ^ (rw & 31))] = crow[kk];
            }
        }
        __syncthreads();
        {
            int kb = tid >> 6;
            #pragma unroll
            for (int w = 0; w < 32; w++) {
                int kk = kb * 32 + w;
                int k  = kc * 128 + kk;
                size_t o = ((size_t)b * DQ + k) * TQ + t0 + rr;
                float cv = c2[rr * 128 + (kk ^ (rr & 31))];
                float r_old = src[o];
                float e  = r_old - cv;
                lsum += (double)e * (double)e;
                float tt = cv - r_old;
                float qs = r_old + tt;
                float rn2 = r_old - qs;
                if (q < QQ - 1) res[o] = rn2;
                else            res[o] = x[o] - rn2;
            }
        }
    }
    #pragma unroll
    for (int m = 32; m >= 1; m >>= 1) lsum += __shfl_xor(lsum, m, 64);
    if ((tid & 63) == 0) redbuf[tid >> 6] = lsum;
    __syncthreads();
    if (tid == 0)
        atomicAdd(loss_acc + q, redbuf[0] + redbuf[1] + redbuf[2] + redbuf[3]);
}

// ---------------------------------------------------------------------------
// Scalars: usage%, loss, perplexity averaged over Q (proven).
__global__ void finalize_kernel(const int* __restrict__ hist,
                                const double* __restrict__ loss_acc,
                                float* __restrict__ outs) {
    int lane = threadIdx.x;  // blockDim = 64
    float usage_sum = 0.f, perp_sum = 0.f;
    for (int q = 0; q < QQ; q++) {
        int nz = 0; float ent = 0.f;
        for (int v = lane; v < VQ; v += 64) {
            int c = hist[q * VQ + v];
            if (c > 0) {
                nz++;
                float p = (float)c / (float)NQ;
                ent += p * logf(p);
            }
        }
        #pragma unroll
        for (int m = 32; m >= 1; m >>= 1) {
            nz  += __shfl_xor(nz, m, 64);
            ent += __shfl_xor(ent, m, 64);
        }
        usage_sum += (float)nz / (float)VQ * 100.f;
        perp_sum  += expf(-ent);
    }
    if (lane == 0) {
        outs[0] = usage_sum / QQ;
        double ls = 0.0;
        for (int q = 0; q < QQ; q++)
            ls += loss_acc[q] * 1.25 / (double)NDQ;
        outs[1] = (float)(ls / QQ);
        outs[2] = perp_sum / QQ;
    }
}

// ---------------------------------------------------------------------------
extern "C" void kernel_launch(void* const* d_in, const int* in_sizes, int n_in,
                              void* d_out, int out_size, void* d_ws, size_t ws_size,
                              hipStream_t stream) {
    const float* x  = (const float*)d_in[0];
    const float* cb = (const float*)d_in[1];

    float* res     = (float*)d_out;          // [0, ND): residual -> quantized_out
    float* scal    = res + NDQ;              // usage, loss, perp
    float* idx_out = scal + 3;               // (B,T,Q) indices as float

    // fast-path ws layout: hist | loss | nflag | cn32 | flag_list
    const size_t need_fast = (size_t)QQ * VQ * 4 + QQ * 8 + 8 * 4
                           + (size_t)QQ * VQ * 4 + (size_t)NQ * 4;

    if (ws_size >= need_fast) {
        int*    hist      = (int*)d_ws;
        double* loss_acc  = (double*)(hist + QQ * VQ);
        int*    nflag     = (int*)(loss_acc + QQ);
        float*  cn32      = (float*)(nflag + 8);
        int*    flag_list = (int*)(cn32 + QQ * VQ);

        hipMemsetAsync(d_ws, 0,
                       QQ * VQ * sizeof(int) + QQ * sizeof(double) + 8 * sizeof(int),
                       stream);
        cnorm32_kernel<<<(QQ * VQ) / 8, 256, 0, stream>>>(cb, cn32);

        for (int q = 0; q < QQ; q++) {
            const float* srcq = (q == 0) ? x : res;
            mfma_pass<<<NQ / 128, 512, 0, stream>>>(srcq, cb, cn32, idx_out,
                                                    nflag, flag_list, q);
            refine_pass<<<256, 256, 0, stream>>>(srcq, cb, cn32, idx_out,
                                                 nflag, flag_list, q);
            phase2_pass<<<NQ / 64, 256, 0, stream>>>(x, cb, srcq, res, idx_out,
                                                     hist, loss_acc, q);
        }
        finalize_kernel<<<1, 64, 0, stream>>>(hist, loss_acc, scal);
    } else {
        // proven fp32 fallback (round-6 path)
        int*    hist     = (int*)d_ws;
        double* loss_acc = (double*)((char*)d_ws + QQ * VQ * sizeof(int));
        float*  cn32     = (float*)(loss_acc + QQ);

        hipMemsetAsync(d_ws, 0, QQ * VQ * sizeof(int) + QQ * sizeof(double), stream);
        cnorm32_kernel<<<(QQ * VQ) / 8, 256, 0, stream>>>(cb, cn32);
        for (int q = 0; q < QQ; q++)
            vq32_fallback<<<NQ / 64, 256, 0, stream>>>(x, cb, cn32, res, idx_out,
                                                       hist, loss_acc, q);
        finalize_kernel<<<1, 64, 0, stream>>>(hist, loss_acc, scal);
    }
}